// Round 8
// baseline (517.932 us; speedup 1.0000x reference)
//
#include <hip/hip_runtime.h>

typedef unsigned short u16;
typedef unsigned char  u8;
typedef unsigned long long u64;

using bf16x8 = __attribute__((ext_vector_type(8))) short;
using f32x4  = __attribute__((ext_vector_type(4))) float;

static __device__ __forceinline__ u16 f2bf(float f) {
  union { float f; unsigned u; } v; v.f = f;
  unsigned r = v.u + 0x7fffu + ((v.u >> 16) & 1u);   // RNE
  return (u16)(r >> 16);
}

// async global->LDS, 16B per lane. LDS dest must be wave-uniform base + lane*16.
static __device__ __forceinline__ void gload_lds16(const void* g, void* l) {
  __builtin_amdgcn_global_load_lds((const __attribute__((address_space(1))) void*)g,
                                   (__attribute__((address_space(3))) void*)l, 16, 0, 0);
}

// ---------------- f32 -> bf16 convert (vectorized) ----------------
__global__ __launch_bounds__(256) void cvt_bf16_kernel(const float4* __restrict__ in,
                                                       ushort4* __restrict__ out, int n4) {
  int i = blockIdx.x * 256 + threadIdx.x;
  if (i >= n4) return;
  float4 v = in[i];
  ushort4 o;
  o.x = f2bf(v.x); o.y = f2bf(v.y); o.z = f2bf(v.z); o.w = f2bf(v.w);
  out[i] = o;
}

// ---------------- zero-fill fallback (ws too small diagnostic) ----------------
__global__ __launch_bounds__(256) void zero_out_kernel(float* __restrict__ out, int n) {
  int i = blockIdx.x * 256 + threadIdx.x;
  if (i < n) out[i] = 0.f;
}

// ---------------- mask pack with per-block layout detection ----------------
// JAX bool may land as u8 (1B) or int32 (4B). Per-block detection: under int32
// little-endian 0/1, bytes at idx%4!=0 are ALWAYS zero (deterministic). Under
// u8 random 0/1, P(192 sampled bytes all zero) = 2^-192 per block. Blocks
// decide independently; disagreement probability ~0.
// Each block packs 256 elements -> 4 u64 words (word w bit i = mask[w*64+i]!=0).
__global__ __launch_bounds__(256) void mask_pack_kernel(const void* __restrict__ mask,
                                                        u64* __restrict__ out) {
  __shared__ int nz;
  const int tid = threadIdx.x, b = blockIdx.x;
  if (tid == 0) nz = 0;
  __syncthreads();
  const int idx = b * 256 + tid;
  const u8 byte = ((const u8*)mask)[idx];
  if ((idx & 3) && byte) atomicAdd(&nz, 1);
  __syncthreads();
  int m;
  if (nz == 0) m = ((const int*)mask)[idx] != 0;   // int32 layout
  else         m = byte != 0;                       // u8 layout
  u64 bits = __ballot(m);
  if ((tid & 63) == 0) out[b * 4 + (tid >> 6)] = bits;
}

// ---------------- bf16 BT-GEMM: C[M,N] = A[M,K] * B[N,K]^T + bias ----------------
// 128x128 tile, BK=64, 4 waves (2x2), each wave 64x64 via 4x4 frags of 16x16x32.
// m97 structure (874 TF verified); T2 swizzle deliberately NOT applied (measured
// null on the 2-phase 128^2 structure — m228d regime gate).
template<bool OUT_BF16>
__global__ __launch_bounds__(256, 2)
void gemm_bt(const u16* __restrict__ A, const u16* __restrict__ Bm,
             const float* __restrict__ bias, void* __restrict__ Cout,
             int M, int N, int K) {
  constexpr int BK = 64;
  __shared__ u16 lA[128 * BK];
  __shared__ u16 lB[128 * BK];
  const int tid = threadIdx.x;
  const int wv = tid >> 6, lane = tid & 63;
  const int wr = (wv >> 1) * 64, wc = (wv & 1) * 64;
  const int bm = blockIdx.x * 128, bn = blockIdx.y * 128;
  const int frow = lane & 15, fk = (lane >> 4) * 8;
  const int srow = tid >> 3;          // 0..31 staging row
  const int scol = (tid & 7) * 8;     // staging col (elements)
  const u16* ga = A + (size_t)(bm + srow) * K + scol;
  const u16* gb = Bm + (size_t)(bn + srow) * K + scol;
  u16* la = &lA[srow * BK + scol];
  u16* lb = &lB[srow * BK + scol];

  f32x4 acc[4][4] = {};

  for (int k0 = 0; k0 < K; k0 += BK) {
#pragma unroll
    for (int r = 0; r < 4; ++r) {
      gload_lds16(ga + (size_t)(r * 32) * K + k0, la + r * 32 * BK);
      gload_lds16(gb + (size_t)(r * 32) * K + k0, lb + r * 32 * BK);
    }
    __syncthreads();
#pragma unroll
    for (int kk = 0; kk < 2; ++kk) {
      bf16x8 af[4], bf[4];
#pragma unroll
      for (int m = 0; m < 4; ++m)
        af[m] = *(const bf16x8*)&lA[(wr + m * 16 + frow) * BK + kk * 32 + fk];
#pragma unroll
      for (int n = 0; n < 4; ++n)
        bf[n] = *(const bf16x8*)&lB[(wc + n * 16 + frow) * BK + kk * 32 + fk];
#pragma unroll
      for (int m = 0; m < 4; ++m)
#pragma unroll
        for (int n = 0; n < 4; ++n)
          acc[m][n] = __builtin_amdgcn_mfma_f32_16x16x32_bf16(af[m], bf[n], acc[m][n], 0, 0, 0);
    }
    __syncthreads();
  }
  // epilogue: C/D layout col=lane&15, row=(lane>>4)*4+reg  [m89/m91 verified]
#pragma unroll
  for (int n = 0; n < 4; ++n) {
    const int col = bn + wc + n * 16 + frow;
    const float bv = bias[col];
#pragma unroll
    for (int m = 0; m < 4; ++m) {
      const int row0 = bm + wr + m * 16 + (lane >> 4) * 4;
#pragma unroll
      for (int r = 0; r < 4; ++r) {
        float v = acc[m][n][r] + bv;
        if constexpr (OUT_BF16)
          ((u16*)Cout)[(size_t)(row0 + r) * N + col] = f2bf(v);
        else
          ((float*)Cout)[(size_t)(row0 + r) * N + col] = v;
      }
    }
  }
}

// ---------------- flash attention with prev-bias + packed bool mask ----------------
// grid = B*H*16 blocks; block = (b,h,qt) handles 64 q-rows. 4 waves, wave w owns
// q-rows w*16..w*16+15. K/V/prev tiles of 64 staged per iteration; online softmax fp32.
//
// LDS swizzles (all both-sides involutions, rule #21):
//  lQ/lK: rows are 128B = 0 mod 32 banks -> naive frag read uses 16 banks (2x floor).
//    Fix: stage with pre-swizzled GLOBAL column (scol8 ^ ((srow&7)<<3)), linear LDS
//    dest; read col' = col ^ ((frow&7)<<3). Post-swizzle: 32 banks, 8 dwords/bank.
//  lVT: V^T, elem(d,k) -> lVT[d*64 + (k ^ (((d>>3)&7)<<3))]; writes 32 banks
//    2-lanes-per-dword (free), reads at data floor.
//  lPrev: 64x64 fp32 tile staged via 4x global_load_lds16/thread instead of
//    16 scalar VMEM/lane (4x fewer VMEM instrs, no VGPR round-trip, -24 VGPRs).
//    Store LDS[row][c] = prev[row][c ^ sw(row)], sw(row)=((row>>2)&3)<<4; staging
//    wave w has sw = w<<4 uniformly. Read prev[row][col] = LDS[row][col^sw]:
//    banks 2-way only (free, m136).
//
// __launch_bounds__(256,3): VGPR cap 170 -> no spill by construction ((256,4)'s
// cap-128 was borderline vs ~110-160 live = spill risk inside hot loop).
// LDS 50176B x 3 blocks/CU = 147KB <= 160KB.
__global__ __launch_bounds__(256, 3)
void attn_kernel(const u16* __restrict__ qkv,   // [4096][3072] bf16 (h*192 + {q,k,v})
                 const float* __restrict__ prev,
                 const u64* __restrict__ mbits, // packed mask [S][S/64]
                 u16* __restrict__ vals) {      // [4096][1024] bf16
  constexpr int S = 1024;
  __shared__ u16 lQ[64 * 64];
  __shared__ u16 lK[64 * 64];
  __shared__ u16 lVT[64 * 64];      // [d][k_swizzled]
  __shared__ u16 lP[4][16 * 72];    // per-wave P [q][k], stride 72
  __shared__ float lPrev[64 * 64];  // [q][col_swizzled]
  const int tid = threadIdx.x, wv = tid >> 6, lane = tid & 63;
  const int bh = blockIdx.x >> 4;          // b*16+h
  const int qt = blockIdx.x & 15;
  const int b = bh >> 4, h = bh & 15;
  const int frow = lane & 15, fkg = lane >> 4, fk = fkg * 8;
  const int srow = tid >> 3, scol8 = (tid & 7) * 8;
  const size_t rowQ0 = (size_t)(b * S + qt * 64);

  // staging-side swizzled global column for Q/K ((srow+32)&7 == srow&7)
  const int scol_sw = scol8 ^ ((srow & 7) << 3);
  // read-side swizzled columns for QK^T frags (loop-invariant)
  const int c0 = fk ^ ((frow & 7) << 3);          // kk=0
  const int c1 = (fk + 32) ^ ((frow & 7) << 3);   // kk=1

  // stage Q once (pre-swizzled source -> linear LDS dest)
  {
    const u16* g = qkv + (rowQ0 + srow) * 3072 + h * 192 + scol_sw;
    gload_lds16(g, &lQ[srow * 64 + scol8]);
    gload_lds16(g + (size_t)32 * 3072, &lQ[(srow + 32) * 64 + scol8]);
  }
  __syncthreads();
  bf16x8 qf0 = *(const bf16x8*)&lQ[(wv * 16 + frow) * 64 + c0];
  bf16x8 qf1 = *(const bf16x8*)&lQ[(wv * 16 + frow) * 64 + c1];

  float m_run[4], l_run[4];
  f32x4 acc_o[4] = {};
#pragma unroll
  for (int r = 0; r < 4; ++r) { m_run[r] = -3e38f; l_run[r] = 0.f; }

  const int qloc = wv * 16 + fkg * 4;   // this lane's q-row base (regs r=0..3)
  const u64* mrow = mbits + (size_t)(qt * 64 + qloc) * (S / 64);

  // prev staging constants: instruction i stages rows i*16 + wv*4 + (lane>>4),
  // wave-uniform source col swizzle sw = wv<<4 (see header comment).
  const float* prevt = prev + ((size_t)bh * S + qt * 64) * S;   // + row*S + kt*64 + colg
  const int prow_s = wv * 4 + (lane >> 4);
  const int pcolg = ((lane & 15) * 4) ^ (wv << 4);
  // prev read swizzle for this lane: sw(qloc+r) = fkg<<4 for r<4
  const int prd = fkg << 4;

  // V-swizzle constant for this lane (staging side): d = scol8+j => d>>3 == tid&7
  const int vsw = (tid & 7) << 3;

  for (int kt = 0; kt < 16; ++kt) {
    __syncthreads();   // previous tile fully consumed
    // V global reads issued FIRST (their latency covers the async issues below)
    const u16* gv = qkv + (size_t)(b * S + kt * 64 + srow) * 3072 + h * 192 + 128 + scol8;
    bf16x8 v0 = *(const bf16x8*)gv;
    bf16x8 v1 = *(const bf16x8*)(gv + (size_t)32 * 3072);
    {  // stage K tile (pre-swizzled source -> linear LDS dest, async)
      const u16* g = qkv + (size_t)(b * S + kt * 64 + srow) * 3072 + h * 192 + 64 + scol_sw;
      gload_lds16(g, &lK[srow * 64 + scol8]);
      gload_lds16(g + (size_t)32 * 3072, &lK[(srow + 32) * 64 + scol8]);
    }
    {  // stage prev tile (64x64 fp32) via 4 async 16B loads/thread
      const float* p0 = prevt + (size_t)kt * 64 + pcolg;
#pragma unroll
      for (int i = 0; i < 4; ++i)
        gload_lds16(p0 + (size_t)(i * 16 + prow_s) * S, &lPrev[(i * 256 + tid) * 4]);
    }
    {  // V^T scatter to LDS with k-swizzle (conflict-free: 32 banks, 2 lanes/dword)
      const int k0 = srow ^ vsw;
      const int k1 = (srow + 32) ^ vsw;
#pragma unroll
      for (int j = 0; j < 8; ++j) {
        lVT[(scol8 + j) * 64 + k0] = (u16)v0[j];
        lVT[(scol8 + j) * 64 + k1] = (u16)v1[j];
      }
    }
    __syncthreads();   // staging complete (drains gload_lds + ds_writes)
    // mask words: issued after barrier, overlap QK^T (L3-resident, 128KB total)
    u64 mw[4];
#pragma unroll
    for (int r = 0; r < 4; ++r) mw[r] = mrow[r * (S / 64) + kt];
    // S = Q K^T  (BT-form; swizzled frag reads, full 32-bank spread)
    f32x4 s[4];
#pragma unroll
    for (int n = 0; n < 4; ++n) {
      bf16x8 kf0 = *(const bf16x8*)&lK[(n * 16 + frow) * 64 + c0];
      bf16x8 kf1 = *(const bf16x8*)&lK[(n * 16 + frow) * 64 + c1];
      f32x4 z = {0.f, 0.f, 0.f, 0.f};
      z = __builtin_amdgcn_mfma_f32_16x16x32_bf16(qf0, kf0, z, 0, 0, 0);
      s[n] = __builtin_amdgcn_mfma_f32_16x16x32_bf16(qf1, kf1, z, 0, 0, 0);
    }
    // scores = s/32 + prev(LDS), masked -> -1e30
#pragma unroll
    for (int r = 0; r < 4; ++r) {
      const u64 t = mw[r] >> frow;   // bit n*16 of t == mask bit n*16+frow
      const int prbase = (qloc + r) * 64;
#pragma unroll
      for (int n = 0; n < 4; ++n) {
        float pv = lPrev[prbase + ((n * 16 + frow) ^ prd)];
        float sc = s[n][r] * 0.03125f + pv;
        s[n][r] = ((t >> (n * 16)) & 1ull) ? -1e30f : sc;
      }
    }
    // row max across 16 lanes (cols) + 4 frags
    float tmax[4];
#pragma unroll
    for (int r = 0; r < 4; ++r) {
      float t = fmaxf(fmaxf(s[0][r], s[1][r]), fmaxf(s[2][r], s[3][r]));
      t = fmaxf(t, __shfl_xor(t, 1));
      t = fmaxf(t, __shfl_xor(t, 2));
      t = fmaxf(t, __shfl_xor(t, 4));
      t = fmaxf(t, __shfl_xor(t, 8));
      tmax[r] = t;
    }
    // online softmax update
    float psum[4];
#pragma unroll
    for (int r = 0; r < 4; ++r) {
      float mnew = fmaxf(m_run[r], tmax[r]);
      float sc = __expf(m_run[r] - mnew);
      m_run[r] = mnew;
      l_run[r] *= sc;
#pragma unroll
      for (int dn = 0; dn < 4; ++dn) acc_o[dn][r] *= sc;
      float ps = 0.f;
#pragma unroll
      for (int n = 0; n < 4; ++n) {
        float p = __expf(s[n][r] - mnew);
        s[n][r] = p;
        ps += p;
      }
      psum[r] = ps;
    }
#pragma unroll
    for (int r = 0; r < 4; ++r) {
      float t = psum[r];
      t += __shfl_xor(t, 1); t += __shfl_xor(t, 2);
      t += __shfl_xor(t, 4); t += __shfl_xor(t, 8);
      l_run[r] += t;
    }
    // P -> per-wave LDS (bf16), transposing frag layout to A-operand layout
    u16* pw = &lP[wv][0];
#pragma unroll
    for (int n = 0; n < 4; ++n)
#pragma unroll
      for (int r = 0; r < 4; ++r)
        pw[(fkg * 4 + r) * 72 + n * 16 + frow] = f2bf(s[n][r]);
    bf16x8 pf0 = *(const bf16x8*)&pw[frow * 72 + fk];
    bf16x8 pf1 = *(const bf16x8*)&pw[frow * 72 + 32 + fk];
    // O += P V   (B-operand from swizzled transposed V)
#pragma unroll
    for (int dn = 0; dn < 4; ++dn) {
      const int d = dn * 16 + frow;
      const int sw = ((dn * 2 + (frow >> 3)) & 7) << 3;   // ((d>>3)&7)<<3
      bf16x8 vt0 = *(const bf16x8*)&lVT[d * 64 + (fk ^ sw)];
      bf16x8 vt1 = *(const bf16x8*)&lVT[d * 64 + ((fk + 32) ^ sw)];
      acc_o[dn] = __builtin_amdgcn_mfma_f32_16x16x32_bf16(pf0, vt0, acc_o[dn], 0, 0, 0);
      acc_o[dn] = __builtin_amdgcn_mfma_f32_16x16x32_bf16(pf1, vt1, acc_o[dn], 0, 0, 0);
    }
  }
  // epilogue: vals[b*S + q][h*64 + d] = O / l
#pragma unroll
  for (int r = 0; r < 4; ++r) {
    float inv = 1.0f / l_run[r];
    size_t row = (rowQ0 + qloc + r) * 1024 + h * 64;
#pragma unroll
    for (int dn = 0; dn < 4; ++dn)
      vals[row + dn * 16 + frow] = f2bf(acc_o[dn][r] * inv);
  }
}

extern "C" void kernel_launch(void* const* d_in, const int* in_sizes, int n_in,
                              void* d_out, int out_size, void* d_ws, size_t ws_size,
                              hipStream_t stream) {
  const float* x     = (const float*)d_in[0];
  const void*  mask  = d_in[1];                // layout detected per-block in pack
  const float* prev  = (const float*)d_in[2];
  const float* qkv_w = (const float*)d_in[3];
  const float* qkv_b = (const float*)d_in[4];
  const float* o_w   = (const float*)d_in[5];
  const float* o_b   = (const float*)d_in[6];

  // ws guard: emit zeros instead of OOB-writing if scratch is too small
  // (measured ws >= 1GB via fill counters; guard kept as tripwire).
  const size_t WS_NEEDED = 41943040 + 131072;
  if (ws_size < WS_NEEDED) {
    zero_out_kernel<<<(out_size + 255) / 256, 256, 0, stream>>>((float*)d_out, out_size);
    return;
  }

  char* ws = (char*)d_ws;
  // region A [0, 8MB): x_bf16, later reused for vals_bf16
  u16* x_bf  = (u16*)(ws);
  u16* vals  = (u16*)(ws);
  // region B [8MB, 14MB): qkv_w bf16 during gemm1; o_w bf16 after (stream-ordered)
  u16* qw_bf = (u16*)(ws + 8388608);
  u16* ow_bf = (u16*)(ws + 8388608);
  // region C [14MB, 38MB): qkv output bf16 [4096][3072]
  u16* qkv_o = (u16*)(ws + 14680064);
  // region D [40MB, 40MB+128KB): packed mask (no aliasing -> pack runs early)
  u64* mask_b = (u64*)(ws + 41943040);

  mask_pack_kernel<<<4096, 256, 0, stream>>>(mask, mask_b);
  cvt_bf16_kernel<<<4096, 256, 0, stream>>>((const float4*)x, (ushort4*)x_bf, 1048576);
  cvt_bf16_kernel<<<3072, 256, 0, stream>>>((const float4*)qkv_w, (ushort4*)qw_bf, 786432);

  dim3 g1(32, 24);
  gemm_bt<true><<<g1, 256, 0, stream>>>(x_bf, qw_bf, qkv_b, qkv_o, 4096, 3072, 1024);

  // region-B reuse below is stream-ordered after gemm1
  cvt_bf16_kernel<<<1024, 256, 0, stream>>>((const float4*)o_w, (ushort4*)ow_bf, 262144);

  attn_kernel<<<1024, 256, 0, stream>>>(qkv_o, prev, mask_b, vals);

  dim3 g2(32, 8);
  gemm_bt<false><<<g2, 256, 0, stream>>>(vals, ow_bf, o_b, d_out, 4096, 1024, 1024);
}

// Round 9
// 500.555 us; speedup vs baseline: 1.0347x; 1.0347x over previous
//
#include <hip/hip_runtime.h>

typedef unsigned short u16;
typedef unsigned char  u8;
typedef unsigned long long u64;

using bf16x8 = __attribute__((ext_vector_type(8))) short;
using f32x4  = __attribute__((ext_vector_type(4))) float;

static __device__ __forceinline__ u16 f2bf(float f) {
  union { float f; unsigned u; } v; v.f = f;
  unsigned r = v.u + 0x7fffu + ((v.u >> 16) & 1u);   // RNE
  return (u16)(r >> 16);
}

// async global->LDS, 16B per lane. LDS dest must be wave-uniform base + lane*16.
static __device__ __forceinline__ void gload_lds16(const void* g, void* l) {
  __builtin_amdgcn_global_load_lds((const __attribute__((address_space(1))) void*)g,
                                   (__attribute__((address_space(3))) void*)l, 16, 0, 0);
}

// ---------------- f32 -> bf16 convert (vectorized) ----------------
__global__ __launch_bounds__(256) void cvt_bf16_kernel(const float4* __restrict__ in,
                                                       ushort4* __restrict__ out, int n4) {
  int i = blockIdx.x * 256 + threadIdx.x;
  if (i >= n4) return;
  float4 v = in[i];
  ushort4 o;
  o.x = f2bf(v.x); o.y = f2bf(v.y); o.z = f2bf(v.z); o.w = f2bf(v.w);
  out[i] = o;
}

// ---------------- zero-fill fallback (ws too small diagnostic) ----------------
__global__ __launch_bounds__(256) void zero_out_kernel(float* __restrict__ out, int n) {
  int i = blockIdx.x * 256 + threadIdx.x;
  if (i < n) out[i] = 0.f;
}

// ---------------- mask pack with per-block layout detection ----------------
// (unchanged from R8 — validated)
__global__ __launch_bounds__(256) void mask_pack_kernel(const void* __restrict__ mask,
                                                        u64* __restrict__ out) {
  __shared__ int nz;
  const int tid = threadIdx.x, b = blockIdx.x;
  if (tid == 0) nz = 0;
  __syncthreads();
  const int idx = b * 256 + tid;
  const u8 byte = ((const u8*)mask)[idx];
  if ((idx & 3) && byte) atomicAdd(&nz, 1);
  __syncthreads();
  int m;
  if (nz == 0) m = ((const int*)mask)[idx] != 0;   // int32 layout
  else         m = byte != 0;                       // u8 layout
  u64 bits = __ballot(m);
  if ((tid & 63) == 0) out[b * 4 + (tid >> 6)] = bits;
}

// ---------------- bf16 BT-GEMM (unchanged from R8 — validated) ----------------
template<bool OUT_BF16>
__global__ __launch_bounds__(256, 2)
void gemm_bt(const u16* __restrict__ A, const u16* __restrict__ Bm,
             const float* __restrict__ bias, void* __restrict__ Cout,
             int M, int N, int K) {
  constexpr int BK = 64;
  __shared__ u16 lA[128 * BK];
  __shared__ u16 lB[128 * BK];
  const int tid = threadIdx.x;
  const int wv = tid >> 6, lane = tid & 63;
  const int wr = (wv >> 1) * 64, wc = (wv & 1) * 64;
  const int bm = blockIdx.x * 128, bn = blockIdx.y * 128;
  const int frow = lane & 15, fk = (lane >> 4) * 8;
  const int srow = tid >> 3;          // 0..31 staging row
  const int scol = (tid & 7) * 8;     // staging col (elements)
  const u16* ga = A + (size_t)(bm + srow) * K + scol;
  const u16* gb = Bm + (size_t)(bn + srow) * K + scol;
  u16* la = &lA[srow * BK + scol];
  u16* lb = &lB[srow * BK + scol];

  f32x4 acc[4][4] = {};

  for (int k0 = 0; k0 < K; k0 += BK) {
#pragma unroll
    for (int r = 0; r < 4; ++r) {
      gload_lds16(ga + (size_t)(r * 32) * K + k0, la + r * 32 * BK);
      gload_lds16(gb + (size_t)(r * 32) * K + k0, lb + r * 32 * BK);
    }
    __syncthreads();
#pragma unroll
    for (int kk = 0; kk < 2; ++kk) {
      bf16x8 af[4], bf[4];
#pragma unroll
      for (int m = 0; m < 4; ++m)
        af[m] = *(const bf16x8*)&lA[(wr + m * 16 + frow) * BK + kk * 32 + fk];
#pragma unroll
      for (int n = 0; n < 4; ++n)
        bf[n] = *(const bf16x8*)&lB[(wc + n * 16 + frow) * BK + kk * 32 + fk];
#pragma unroll
      for (int m = 0; m < 4; ++m)
#pragma unroll
        for (int n = 0; n < 4; ++n)
          acc[m][n] = __builtin_amdgcn_mfma_f32_16x16x32_bf16(af[m], bf[n], acc[m][n], 0, 0, 0);
    }
    __syncthreads();
  }
#pragma unroll
  for (int n = 0; n < 4; ++n) {
    const int col = bn + wc + n * 16 + frow;
    const float bv = bias[col];
#pragma unroll
    for (int m = 0; m < 4; ++m) {
      const int row0 = bm + wr + m * 16 + (lane >> 4) * 4;
#pragma unroll
      for (int r = 0; r < 4; ++r) {
        float v = acc[m][n][r] + bv;
        if constexpr (OUT_BF16)
          ((u16*)Cout)[(size_t)(row0 + r) * N + col] = f2bf(v);
        else
          ((float*)Cout)[(size_t)(row0 + r) * N + col] = v;
      }
    }
  }
}

// ---------------- pipelined flash attention (2-phase dbuf, 1 barrier/tile) --------
// R9 change: K dbuf via gload_lds; V^T dbuf via reg-stage (issue loads phase A,
// ds_write phase F after QK^T — T14 issue-early/use-late); prev+mask preloaded one
// tile ahead into regs (R5-validated scalar path; R8 proved LDS-staging neutral).
// ONE __syncthreads per tile: the compiler's vmcnt(0) drain at the barrier now sits
// AFTER compute, so next-tile loads fly during compute (T3 minimum-2-phase recipe).
// Pipeline: tile t's K/V/prev issued at iter t-1; consumed at iter t. Each LDS half
// written at iter t was last read at iter t-1 (barrier between) — race-free.
// LDS = 8192(lQ) + 16384(lK dbuf) + 16384(lVT dbuf) + 9216(lP) = 50176 B -> 3 blocks/CU.
__global__ __launch_bounds__(256, 3)
void attn_kernel(const u16* __restrict__ qkv,   // [4096][3072] bf16 (h*192 + {q,k,v})
                 const float* __restrict__ prev,
                 const u64* __restrict__ mbits, // packed mask [S][S/64]
                 u16* __restrict__ vals) {      // [4096][1024] bf16
  constexpr int S = 1024;
  __shared__ u16 lQ[64 * 64];
  __shared__ u16 lK[2][64 * 64];
  __shared__ u16 lVT[2][64 * 64];   // [d][k_swizzled]
  __shared__ u16 lP[4][16 * 72];    // per-wave P [q][k], stride 72
  const int tid = threadIdx.x, wv = tid >> 6, lane = tid & 63;
  const int bh = blockIdx.x >> 4;          // b*16+h
  const int qt = blockIdx.x & 15;
  const int b = bh >> 4, h = bh & 15;
  const int frow = lane & 15, fkg = lane >> 4, fk = fkg * 8;
  const int srow = tid >> 3, scol8 = (tid & 7) * 8;
  const size_t rowQ0 = (size_t)(b * S + qt * 64);

  // staging-side swizzled global column for Q/K ((srow+32)&7 == srow&7)
  const int scol_sw = scol8 ^ ((srow & 7) << 3);
  // read-side swizzled columns for QK^T frags (loop-invariant)
  const int c0 = fk ^ ((frow & 7) << 3);          // kk=0
  const int c1 = (fk + 32) ^ ((frow & 7) << 3);   // kk=1
  // V-swizzle constant (staging side): d = scol8+j => d>>3 == tid&7
  const int vsw = (tid & 7) << 3;

  const int qloc = wv * 16 + fkg * 4;   // this lane's q-row base (regs r=0..3)
  const u64* mrow = mbits + (size_t)(qt * 64 + qloc) * (S / 64);
  const float* prow = prev + ((size_t)bh * S + qt * 64 + qloc) * S;

  // ---- prologue: stage Q, K(0), V(0)->VT[0], prev(0)/mask(0) regs ----
  {
    const u16* g = qkv + (rowQ0 + srow) * 3072 + h * 192 + scol_sw;
    gload_lds16(g, &lQ[srow * 64 + scol8]);
    gload_lds16(g + (size_t)32 * 3072, &lQ[(srow + 32) * 64 + scol8]);
  }
  {
    const u16* g = qkv + (size_t)(b * S + srow) * 3072 + h * 192 + 64 + scol_sw;
    gload_lds16(g, &lK[0][srow * 64 + scol8]);
    gload_lds16(g + (size_t)32 * 3072, &lK[0][(srow + 32) * 64 + scol8]);
  }
  bf16x8 v0, v1;
  {
    const u16* gv = qkv + (size_t)(b * S + srow) * 3072 + h * 192 + 128 + scol8;
    v0 = *(const bf16x8*)gv;
    v1 = *(const bf16x8*)(gv + (size_t)32 * 3072);
    const int k0 = srow ^ vsw, k1 = (srow + 32) ^ vsw;
#pragma unroll
    for (int j = 0; j < 8; ++j) {
      lVT[0][(scol8 + j) * 64 + k0] = (u16)v0[j];
      lVT[0][(scol8 + j) * 64 + k1] = (u16)v1[j];
    }
  }
  float pvraw[4][4];
  u64 mw[4];
#pragma unroll
  for (int r = 0; r < 4; ++r) mw[r] = mrow[r * (S / 64)];
#pragma unroll
  for (int n = 0; n < 4; ++n)
#pragma unroll
    for (int r = 0; r < 4; ++r)
      pvraw[n][r] = prow[(size_t)r * S + n * 16 + frow];
  __syncthreads();

  bf16x8 qf0 = *(const bf16x8*)&lQ[(wv * 16 + frow) * 64 + c0];
  bf16x8 qf1 = *(const bf16x8*)&lQ[(wv * 16 + frow) * 64 + c1];

  float m_run[4], l_run[4];
  f32x4 acc_o[4] = {};
#pragma unroll
  for (int r = 0; r < 4; ++r) { m_run[r] = -3e38f; l_run[r] = 0.f; }

  for (int kt = 0; kt < 16; ++kt) {
    const int cur = kt & 1;
    const bool more = (kt < 15);
    // (A) issue next-tile K gload + V reg loads (latency hides under B..F)
    if (more) {
      const u16* g = qkv + (size_t)(b * S + (kt + 1) * 64 + srow) * 3072 + h * 192 + 64 + scol_sw;
      gload_lds16(g, &lK[cur ^ 1][srow * 64 + scol8]);
      gload_lds16(g + (size_t)32 * 3072, &lK[cur ^ 1][(srow + 32) * 64 + scol8]);
      const u16* gv = qkv + (size_t)(b * S + (kt + 1) * 64 + srow) * 3072 + h * 192 + 128 + scol8;
      v0 = *(const bf16x8*)gv;
      v1 = *(const bf16x8*)(gv + (size_t)32 * 3072);
    }
    // (B) S = Q K^T from lK[cur]
    f32x4 s[4];
#pragma unroll
    for (int n = 0; n < 4; ++n) {
      bf16x8 kf0 = *(const bf16x8*)&lK[cur][(n * 16 + frow) * 64 + c0];
      bf16x8 kf1 = *(const bf16x8*)&lK[cur][(n * 16 + frow) * 64 + c1];
      f32x4 z = {0.f, 0.f, 0.f, 0.f};
      z = __builtin_amdgcn_mfma_f32_16x16x32_bf16(qf0, kf0, z, 0, 0, 0);
      s[n] = __builtin_amdgcn_mfma_f32_16x16x32_bf16(qf1, kf1, z, 0, 0, 0);
    }
    // (C) scores = s/32 + prev (preloaded regs), masked -> -1e30
#pragma unroll
    for (int r = 0; r < 4; ++r) {
      const u64 t = mw[r] >> frow;   // bit n*16 of t == mask bit n*16+frow
#pragma unroll
      for (int n = 0; n < 4; ++n) {
        float sc = s[n][r] * 0.03125f + pvraw[n][r];
        s[n][r] = ((t >> (n * 16)) & 1ull) ? -1e30f : sc;
      }
    }
    // (D) preload next tile's prev/mask into the just-freed regs
    if (more) {
#pragma unroll
      for (int r = 0; r < 4; ++r) mw[r] = mrow[r * (S / 64) + kt + 1];
      const float* pp = prow + (kt + 1) * 64 + frow;
#pragma unroll
      for (int n = 0; n < 4; ++n)
#pragma unroll
        for (int r = 0; r < 4; ++r)
          pvraw[n][r] = pp[(size_t)r * S + n * 16];
    }
    // (E) online softmax update
    float tmax[4];
#pragma unroll
    for (int r = 0; r < 4; ++r) {
      float t = fmaxf(fmaxf(s[0][r], s[1][r]), fmaxf(s[2][r], s[3][r]));
      t = fmaxf(t, __shfl_xor(t, 1));
      t = fmaxf(t, __shfl_xor(t, 2));
      t = fmaxf(t, __shfl_xor(t, 4));
      t = fmaxf(t, __shfl_xor(t, 8));
      tmax[r] = t;
    }
    float psum[4];
#pragma unroll
    for (int r = 0; r < 4; ++r) {
      float mnew = fmaxf(m_run[r], tmax[r]);
      float sc = __expf(m_run[r] - mnew);
      m_run[r] = mnew;
      l_run[r] *= sc;
#pragma unroll
      for (int dn = 0; dn < 4; ++dn) acc_o[dn][r] *= sc;
      float ps = 0.f;
#pragma unroll
      for (int n = 0; n < 4; ++n) {
        float p = __expf(s[n][r] - mnew);
        s[n][r] = p;
        ps += p;
      }
      psum[r] = ps;
    }
#pragma unroll
    for (int r = 0; r < 4; ++r) {
      float t = psum[r];
      t += __shfl_xor(t, 1); t += __shfl_xor(t, 2);
      t += __shfl_xor(t, 4); t += __shfl_xor(t, 8);
      l_run[r] += t;
    }
    // (F) write next tile's V^T (v regs arrived during B..E)
    if (more) {
      const int k0 = srow ^ vsw, k1 = (srow + 32) ^ vsw;
#pragma unroll
      for (int j = 0; j < 8; ++j) {
        lVT[cur ^ 1][(scol8 + j) * 64 + k0] = (u16)v0[j];
        lVT[cur ^ 1][(scol8 + j) * 64 + k1] = (u16)v1[j];
      }
    }
    // (G) P -> lP (bf16, A-operand layout), then O += P V from lVT[cur]
    u16* pw = &lP[wv][0];
#pragma unroll
    for (int n = 0; n < 4; ++n)
#pragma unroll
      for (int r = 0; r < 4; ++r)
        pw[(fkg * 4 + r) * 72 + n * 16 + frow] = f2bf(s[n][r]);
    bf16x8 pf0 = *(const bf16x8*)&pw[frow * 72 + fk];
    bf16x8 pf1 = *(const bf16x8*)&pw[frow * 72 + 32 + fk];
#pragma unroll
    for (int dn = 0; dn < 4; ++dn) {
      const int d = dn * 16 + frow;
      const int sw = ((dn * 2 + (frow >> 3)) & 7) << 3;   // ((d>>3)&7)<<3
      bf16x8 vt0 = *(const bf16x8*)&lVT[cur][d * 64 + (fk ^ sw)];
      bf16x8 vt1 = *(const bf16x8*)&lVT[cur][d * 64 + ((fk + 32) ^ sw)];
      acc_o[dn] = __builtin_amdgcn_mfma_f32_16x16x32_bf16(pf0, vt0, acc_o[dn], 0, 0, 0);
      acc_o[dn] = __builtin_amdgcn_mfma_f32_16x16x32_bf16(pf1, vt1, acc_o[dn], 0, 0, 0);
    }
    // (H) single barrier per tile (drains this iter's prefetch after compute)
    __syncthreads();
  }
  // epilogue: vals[b*S + q][h*64 + d] = O / l
#pragma unroll
  for (int r = 0; r < 4; ++r) {
    float inv = 1.0f / l_run[r];
    size_t row = (rowQ0 + qloc + r) * 1024 + h * 64;
#pragma unroll
    for (int dn = 0; dn < 4; ++dn)
      vals[row + dn * 16 + frow] = f2bf(acc_o[dn][r] * inv);
  }
}

extern "C" void kernel_launch(void* const* d_in, const int* in_sizes, int n_in,
                              void* d_out, int out_size, void* d_ws, size_t ws_size,
                              hipStream_t stream) {
  const float* x     = (const float*)d_in[0];
  const void*  mask  = d_in[1];                // layout detected per-block in pack
  const float* prev  = (const float*)d_in[2];
  const float* qkv_w = (const float*)d_in[3];
  const float* qkv_b = (const float*)d_in[4];
  const float* o_w   = (const float*)d_in[5];
  const float* o_b   = (const float*)d_in[6];

  const size_t WS_NEEDED = 41943040 + 131072;
  if (ws_size < WS_NEEDED) {
    zero_out_kernel<<<(out_size + 255) / 256, 256, 0, stream>>>((float*)d_out, out_size);
    return;
  }

  char* ws = (char*)d_ws;
  // region A [0, 8MB): x_bf16, later reused for vals_bf16
  u16* x_bf  = (u16*)(ws);
  u16* vals  = (u16*)(ws);
  // region B [8MB, 14MB): qkv_w bf16 during gemm1; o_w bf16 after (stream-ordered)
  u16* qw_bf = (u16*)(ws + 8388608);
  u16* ow_bf = (u16*)(ws + 8388608);
  // region C [14MB, 38MB): qkv output bf16 [4096][3072]
  u16* qkv_o = (u16*)(ws + 14680064);
  // region D [40MB, 40MB+128KB): packed mask
  u64* mask_b = (u64*)(ws + 41943040);

  mask_pack_kernel<<<4096, 256, 0, stream>>>(mask, mask_b);
  cvt_bf16_kernel<<<4096, 256, 0, stream>>>((const float4*)x, (ushort4*)x_bf, 1048576);
  cvt_bf16_kernel<<<3072, 256, 0, stream>>>((const float4*)qkv_w, (ushort4*)qw_bf, 786432);

  dim3 g1(32, 24);
  gemm_bt<true><<<g1, 256, 0, stream>>>(x_bf, qw_bf, qkv_b, qkv_o, 4096, 3072, 1024);

  cvt_bf16_kernel<<<1024, 256, 0, stream>>>((const float4*)o_w, (ushort4*)ow_bf, 262144);

  attn_kernel<<<1024, 256, 0, stream>>>(qkv_o, prev, mask_b, vals);

  dim3 g2(32, 8);
  gemm_bt<false><<<g2, 256, 0, stream>>>(vals, ow_bf, o_b, d_out, 4096, 1024, 1024);
}